// Round 7
// baseline (190.705 us; speedup 1.0000x reference)
//
#include <hip/hip_runtime.h>

#define EPS_F 1e-6f
#define BLK   256

typedef float v2f __attribute__((ext_vector_type(2)));
typedef float v4f __attribute__((ext_vector_type(4)));

// ---- Kernel 1: wt[node][20] = sigmoid(w_raw[tree][node]), transposed+padded.
// Stride 20 keeps each tree-PAIR's node weights 8B-aligned -> s_load_dwordx2
// feeds v_pk_fma with a 64-bit scalar operand.
__global__ void sigmoid_w_kernel(const float* __restrict__ w_raw,
                                 float* __restrict__ wt) {
    int i = threadIdx.x;
    if (i < 361) {
        int t = i / 19;      // tree
        int k = i % 19;      // node
        wt[k * 20 + t] = 1.0f / (1.0f + expf(-w_raw[i]));
    }
}

__device__ __forceinline__ v2f vsplat(float s) {
    v2f r; r.x = s; r.y = s; return r;
}

// mix for TWO TREES at once (same sample): w*mn + (1-w)*mx = w*(mn-mx) + mx
// min/max scalarize (2+2 ops); sub and fma pack (v_pk_add + v_pk_fma).
__device__ __forceinline__ v2f pairmix(v2f a, v2f b, v2f wv) {
    v2f mn, mx;
    mn.x = fminf(a.x, b.x); mn.y = fminf(a.y, b.y);
    mx.x = fmaxf(a.x, b.x); mx.y = fmaxf(a.y, b.y);
    return wv * (mn - mx) + mx;
}

__device__ __forceinline__ float clampf(float r) {
    return __builtin_amdgcn_fmed3f(r, EPS_F, 1.0f - EPS_F);  // 1 instr clamp
}

// ---- Kernel 2: 1 sample/thread, trees in v2f PAIRS, VGPR<=64 for 8 waves/SIMD
// __launch_bounds__(256, 8): 8 waves/EU -> allocator budget 64 VGPR; LDS
// 19456 B also allows 8 blocks/CU, so both limits align at full residency.
__global__ __launch_bounds__(BLK, 8) void tree_forward_kernel(
    const float* __restrict__ c20,   // (B, 20)
    const float* __restrict__ wt,    // (19, 20) sigmoid'd, transposed+padded
    float* __restrict__ out,         // (B, 19)
    int B)
{
    __shared__ float so[BLK * 19];   // 19456 B

    const int tid = threadIdx.x;
    const int S0  = blockIdx.x * BLK;
    const int s   = S0 + tid;

    // Layer-0 min/max pairs are tree-independent: compute once.
    float mx[10], d[10];
    {
        const float4* p = reinterpret_cast<const float4*>(c20 + (size_t)s * 20);
        const bool valid = (s < B);
        #pragma unroll
        for (int q = 0; q < 5; ++q) {
            float4 v = valid ? p[q] : make_float4(0.f, 0.f, 0.f, 0.f);
            {
                float mn = fminf(v.x, v.y);
                mx[2*q] = fmaxf(v.x, v.y);
                d[2*q]  = mn - mx[2*q];
            }
            {
                float mn = fminf(v.z, v.w);
                mx[2*q+1] = fmaxf(v.z, v.w);
                d[2*q+1]  = mn - mx[2*q+1];
            }
        }
    }

    float* __restrict__ o = &so[tid * 19];

    // 9 tree pairs; lanes of each v2f hold (tree 2tp, tree 2tp+1).
    // y-pairs are consumed immediately into z[k] to keep the live set small
    // (d/mx 20 + z 10 + transients ~= 50 VGPR -> fits the 64 budget).
    #pragma unroll
    for (int tp = 0; tp < 9; ++tp) {
        const float* wp = wt + 2 * tp;   // uniform; node k pair at wp[20k..20k+1]

        v2f z[5];
        #pragma unroll
        for (int k = 0; k < 5; ++k) {
            v2f w0 = *reinterpret_cast<const v2f*>(wp + 20 * (2*k));
            v2f w1 = *reinterpret_cast<const v2f*>(wp + 20 * (2*k + 1));
            v2f ya = w0 * vsplat(d[2*k])     + vsplat(mx[2*k]);     // v_pk_fma
            v2f yb = w1 * vsplat(d[2*k + 1]) + vsplat(mx[2*k + 1]); // v_pk_fma
            v2f wm = *reinterpret_cast<const v2f*>(wp + 20 * (10 + k));
            z[k] = pairmix(ya, yb, wm);
        }

        v2f u0 = pairmix(z[0], z[1], *reinterpret_cast<const v2f*>(wp + 20 * 15));
        v2f u1 = pairmix(z[2], z[3], *reinterpret_cast<const v2f*>(wp + 20 * 16));
        v2f v  = pairmix(u0, u1,   *reinterpret_cast<const v2f*>(wp + 20 * 17));
        v2f r  = pairmix(v, z[4],  *reinterpret_cast<const v2f*>(wp + 20 * 18));

        o[2*tp]     = clampf(r.x);
        o[2*tp + 1] = clampf(r.y);
    }

    // tree 18 (last, unpaired) — scalar path, same immediate-consume shape
    {
        const float* wr = wt + 18;   // node k at wr[20k]
        float z[5];
        #pragma unroll
        for (int k = 0; k < 5; ++k) {
            float ya = fmaf(wr[20 * (2*k)],     d[2*k],     mx[2*k]);
            float yb = fmaf(wr[20 * (2*k + 1)], d[2*k + 1], mx[2*k + 1]);
            float mn = fminf(ya, yb);
            float mxx = fmaxf(ya, yb);
            z[k] = fmaf(wr[20 * (10 + k)], mn - mxx, mxx);
        }
        float mn, mxx;
        mn = fminf(z[0], z[1]); mxx = fmaxf(z[0], z[1]);
        float u0 = fmaf(wr[20 * 15], mn - mxx, mxx);
        mn = fminf(z[2], z[3]); mxx = fmaxf(z[2], z[3]);
        float u1 = fmaf(wr[20 * 16], mn - mxx, mxx);
        mn = fminf(u0, u1); mxx = fmaxf(u0, u1);
        float v0 = fmaf(wr[20 * 17], mn - mxx, mxx);
        mn = fminf(v0, z[4]); mxx = fmaxf(v0, z[4]);
        float rr = fmaf(wr[20 * 18], mn - mxx, mxx);
        o[18] = clampf(rr);
    }

    __syncthreads();

    // Cooperative coalesced copy-out: BLK*19 = 4864 dwords = 1216 float4, nt.
    const int nDw    = B * 19;          // 1.9e7 fits int32
    const int baseDw = S0 * 19;         // divisible by 4
    const v4f* ls = reinterpret_cast<const v4f*>(so);

    #pragma unroll
    for (int i = tid; i < (BLK * 19) / 4; i += BLK) {
        int g = baseDw + i * 4;
        if (g + 3 < nDw) {
            __builtin_nontemporal_store(ls[i], reinterpret_cast<v4f*>(out + g));
        } else if (g < nDw) {
            v4f v4 = ls[i];
            out[g] = v4.x;
            if (g + 1 < nDw) out[g + 1] = v4.y;
            if (g + 2 < nDw) out[g + 2] = v4.z;
        }
    }
}

extern "C" void kernel_launch(void* const* d_in, const int* in_sizes, int n_in,
                              void* d_out, int out_size, void* d_ws, size_t ws_size,
                              hipStream_t stream) {
    // setup_inputs order: p1 (B,) int, p2 (B,) int, c20 (B,20) f32, w_raw (19,19) f32
    const float* c20   = (const float*)d_in[2];
    const float* w_raw = (const float*)d_in[3];
    float* out = (float*)d_out;
    float* wt  = (float*)d_ws;   // 380 floats of scratch (19x20 transposed)

    int B = in_sizes[0];

    sigmoid_w_kernel<<<1, 384, 0, stream>>>(w_raw, wt);

    int grid = (B + BLK - 1) / BLK;
    tree_forward_kernel<<<grid, BLK, 0, stream>>>(c20, wt, out, B);
}

// Round 9
// 187.028 us; speedup vs baseline: 1.0197x; 1.0197x over previous
//
#include <hip/hip_runtime.h>

#define EPS_F 1e-6f
#define BLK   256

typedef float v2f __attribute__((ext_vector_type(2)));
typedef float v4f __attribute__((ext_vector_type(4)));

// ---- Kernel 1: wt[node][20] = sigmoid(w_raw[tree][node]), transposed+padded.
// Stride 20 keeps each tree-PAIR's node weights 8B-aligned -> s_load_dwordx2
// feeds v_pk_fma with a 64-bit scalar operand.
__global__ void sigmoid_w_kernel(const float* __restrict__ w_raw,
                                 float* __restrict__ wt) {
    int i = threadIdx.x;
    if (i < 361) {
        int t = i / 19;      // tree
        int k = i % 19;      // node
        wt[k * 20 + t] = 1.0f / (1.0f + expf(-w_raw[i]));
    }
}

__device__ __forceinline__ v2f vsplat(float s) {
    v2f r; r.x = s; r.y = s; return r;
}

// mix for TWO TREES at once (same sample): w*mn + (1-w)*mx = w*(mn-mx) + mx
// min/max scalarize (2+2 ops); sub and fma pack (v_pk_add + v_pk_fma).
__device__ __forceinline__ v2f pairmix(v2f a, v2f b, v2f wv) {
    v2f mn, mx;
    mn.x = fminf(a.x, b.x); mn.y = fminf(a.y, b.y);
    mx.x = fmaxf(a.x, b.x); mx.y = fmaxf(a.y, b.y);
    return wv * (mn - mx) + mx;
}

__device__ __forceinline__ float clampf(float r) {
    return __builtin_amdgcn_fmed3f(r, EPS_F, 1.0f - EPS_F);  // 1 instr clamp
}

// ---- Kernel 2: dense cooperative input staging through LDS, then 1 sample/
// thread with trees in v2f PAIRS, LDS output staging, coalesced nt copy-out.
// NO min-waves in launch_bounds (R7 lesson: forcing VGPR below the live set
// triggers catastrophic rematerialization, 3x VALU).
__global__ __launch_bounds__(BLK) void tree_forward_kernel(
    const float* __restrict__ c20,   // (B, 20)
    const float* __restrict__ wt,    // (19, 20) sigmoid'd, transposed+padded
    float* __restrict__ out,         // (B, 19)
    int B)
{
    __shared__ float si[BLK * 20];   // 20480 B input tile (dense-staged)
    __shared__ float so[BLK * 19];   // 19456 B output tile

    const int tid = threadIdx.x;
    const int S0  = blockIdx.x * BLK;

    // ---- Phase 1: dense cooperative staging of the 20 KB input tile.
    // 1280 float4 per block; lane-contiguous global loads (16 lines/instr
    // instead of ~64-80 for the old per-thread 80B-stride pattern).
    {
        const v4f* g4 = reinterpret_cast<const v4f*>(c20) + (size_t)S0 * 5;
        v4f* s4 = reinterpret_cast<v4f*>(si);
        const int lim4 = B * 5;          // total float4 in c20 (5e6, fits int)
        const int base4 = S0 * 5;
        #pragma unroll
        for (int j = 0; j < 5; ++j) {
            int idx = tid + j * BLK;
            v4f v;
            if (base4 + idx < lim4) {
                v = g4[idx];
            } else {
                v.x = 0.f; v.y = 0.f; v.z = 0.f; v.w = 0.f;
            }
            // ds_write_b128, start bank (4*lane)%32: 8 lanes/bank uniform ->
            // zero extra conflict cycles.
            s4[idx] = v;
        }
    }
    __syncthreads();

    // ---- Phase 2: per-thread read-back (5x ds_read_b128 at 80 B stride;
    // start bank (20*lane)%32 spreads 8 lanes/bank -> conflict-free).
    float mx[10], d[10];
    {
        const v4f* r4 = reinterpret_cast<const v4f*>(si + tid * 20);
        #pragma unroll
        for (int q = 0; q < 5; ++q) {
            v4f v = r4[q];
            {
                float mn = fminf(v.x, v.y);
                mx[2*q] = fmaxf(v.x, v.y);
                d[2*q]  = mn - mx[2*q];
            }
            {
                float mn = fminf(v.z, v.w);
                mx[2*q+1] = fmaxf(v.z, v.w);
                d[2*q+1]  = mn - mx[2*q+1];
            }
        }
    }

    float* __restrict__ o = &so[tid * 19];

    // ---- Phase 3: 9 tree pairs; lanes of each v2f hold (tree 2tp, 2tp+1).
    // (identical to the proven R6 loop, VGPR ~68, no allocator pressure)
    #pragma unroll
    for (int tp = 0; tp < 9; ++tp) {
        const float* wp = wt + 2 * tp;   // uniform; node k pair at wp[20k..20k+1]

        v2f y[10];
        #pragma unroll
        for (int k = 0; k < 10; ++k) {
            v2f wk = *reinterpret_cast<const v2f*>(wp + 20 * k); // s_load_dwordx2
            y[k] = wk * vsplat(d[k]) + vsplat(mx[k]);            // 1 v_pk_fma
        }

        v2f z[5];
        #pragma unroll
        for (int k = 0; k < 5; ++k) {
            v2f wk = *reinterpret_cast<const v2f*>(wp + 20 * (10 + k));
            z[k] = pairmix(y[2*k], y[2*k+1], wk);
        }

        v2f u0 = pairmix(z[0], z[1], *reinterpret_cast<const v2f*>(wp + 20 * 15));
        v2f u1 = pairmix(z[2], z[3], *reinterpret_cast<const v2f*>(wp + 20 * 16));
        v2f v  = pairmix(u0, u1,   *reinterpret_cast<const v2f*>(wp + 20 * 17));
        v2f r  = pairmix(v, z[4],  *reinterpret_cast<const v2f*>(wp + 20 * 18));

        o[2*tp]     = clampf(r.x);
        o[2*tp + 1] = clampf(r.y);
    }

    // tree 18 (last, unpaired) — scalar path
    {
        const float* wr = wt + 18;   // node k at wr[20k]
        float y[10];
        #pragma unroll
        for (int k = 0; k < 10; ++k)
            y[k] = fmaf(wr[20 * k], d[k], mx[k]);
        float z[5];
        #pragma unroll
        for (int k = 0; k < 5; ++k) {
            float mn = fminf(y[2*k], y[2*k+1]);
            float mxx = fmaxf(y[2*k], y[2*k+1]);
            z[k] = fmaf(wr[20 * (10 + k)], mn - mxx, mxx);
        }
        float mn, mxx;
        mn = fminf(z[0], z[1]); mxx = fmaxf(z[0], z[1]);
        float u0 = fmaf(wr[20 * 15], mn - mxx, mxx);
        mn = fminf(z[2], z[3]); mxx = fmaxf(z[2], z[3]);
        float u1 = fmaf(wr[20 * 16], mn - mxx, mxx);
        mn = fminf(u0, u1); mxx = fmaxf(u0, u1);
        float v0 = fmaf(wr[20 * 17], mn - mxx, mxx);
        mn = fminf(v0, z[4]); mxx = fmaxf(v0, z[4]);
        float rr = fmaf(wr[20 * 18], mn - mxx, mxx);
        o[18] = clampf(rr);
    }

    __syncthreads();

    // ---- Phase 4: cooperative coalesced copy-out: 1216 float4, nt stores.
    const int nDw    = B * 19;          // 1.9e7 fits int32
    const int baseDw = S0 * 19;         // divisible by 4
    const v4f* ls = reinterpret_cast<const v4f*>(so);

    #pragma unroll
    for (int i = tid; i < (BLK * 19) / 4; i += BLK) {
        int g = baseDw + i * 4;
        if (g + 3 < nDw) {
            __builtin_nontemporal_store(ls[i], reinterpret_cast<v4f*>(out + g));
        } else if (g < nDw) {
            v4f v4 = ls[i];
            out[g] = v4.x;
            if (g + 1 < nDw) out[g + 1] = v4.y;
            if (g + 2 < nDw) out[g + 2] = v4.z;
        }
    }
}

extern "C" void kernel_launch(void* const* d_in, const int* in_sizes, int n_in,
                              void* d_out, int out_size, void* d_ws, size_t ws_size,
                              hipStream_t stream) {
    // setup_inputs order: p1 (B,) int, p2 (B,) int, c20 (B,20) f32, w_raw (19,19) f32
    const float* c20   = (const float*)d_in[2];
    const float* w_raw = (const float*)d_in[3];
    float* out = (float*)d_out;
    float* wt  = (float*)d_ws;   // 380 floats of scratch (19x20 transposed)

    int B = in_sizes[0];

    sigmoid_w_kernel<<<1, 384, 0, stream>>>(w_raw, wt);

    int grid = (B + BLK - 1) / BLK;
    tree_forward_kernel<<<grid, BLK, 0, stream>>>(c20, wt, out, B);
}

// Round 10
// 159.674 us; speedup vs baseline: 1.1943x; 1.1713x over previous
//
#include <hip/hip_runtime.h>

#define EPS_F 1e-6f
#define BLK   256

typedef float v4f __attribute__((ext_vector_type(4)));

// ---- Kernel 1: w = sigmoid(w_raw), 19x19 = 361 floats into d_ws (R0 layout)
__global__ void sigmoid_w_kernel(const float* __restrict__ w_raw,
                                 float* __restrict__ w) {
    int i = threadIdx.x;
    if (i < 361) {
        w[i] = 1.0f / (1.0f + expf(-w_raw[i]));
    }
}

__device__ __forceinline__ float mixf(float a, float b, float wv) {
    float mn = fminf(a, b);
    float mx = fmaxf(a, b);
    return fmaf(wv, mn - mx, mx);   // w*mn + (1-w)*mx
}

__device__ __forceinline__ float clampf(float r) {
    return __builtin_amdgcn_fmed3f(r, EPS_F, 1.0f - EPS_F);  // 1-instr clamp
}

// ---- Kernel 2: dense cooperative input staging -> LDS readback -> R0 scalar
// tree-pair math -> LDS output staging -> coalesced nt copy-out.
// __launch_bounds__(BLK, 4): LDS (39936 B) caps at 4 blocks/CU = 4 waves/EU
// anyway; declaring it gives the allocator a 128-VGPR budget so it does NOT
// squeeze below the live set (R7/R9 lesson: that triggers 3x VALU remat).
__global__ __launch_bounds__(BLK, 4) void tree_forward_kernel(
    const float* __restrict__ c20,   // (B, 20)
    const float* __restrict__ w,     // (19, 19) sigmoid'd
    float* __restrict__ out,         // (B, 19)
    int B)
{
    __shared__ float si[BLK * 20];   // 20480 B input tile (dense-staged)
    __shared__ float so[BLK * 19];   // 19456 B output tile

    const int tid = threadIdx.x;
    const int S0  = blockIdx.x * BLK;

    // ---- Phase 1: dense cooperative staging of the 20 KB input tile.
    // 1280 float4/block, lane-contiguous (16 L1 lines per wave-instruction
    // vs 80 for the per-thread 80B-stride pattern).
    {
        const v4f* g4 = reinterpret_cast<const v4f*>(c20) + (size_t)S0 * 5;
        v4f* s4 = reinterpret_cast<v4f*>(si);
        const int lim4  = B * 5;         // 5e6 float4 total, fits int32
        const int base4 = S0 * 5;
        #pragma unroll
        for (int j = 0; j < 5; ++j) {
            int idx = tid + j * BLK;
            v4f v;
            if (base4 + idx < lim4) {
                v = g4[idx];
            } else {
                v.x = 0.f; v.y = 0.f; v.z = 0.f; v.w = 0.f;
            }
            s4[idx] = v;   // ds_write_b128, 8 lanes/bank uniform -> no conflict
        }
    }
    __syncthreads();

    // ---- Phase 2: per-thread readback: 5x ds_read_b128 at 80 B stride
    // (start bank (20*lane)%32, 8 lanes/bank -> conflict-free), then layer-0.
    float mx[10], d[10];
    {
        const v4f* r4 = reinterpret_cast<const v4f*>(si + tid * 20);
        #pragma unroll
        for (int q = 0; q < 5; ++q) {
            v4f v = r4[q];
            {
                float mn = fminf(v.x, v.y);
                mx[2*q] = fmaxf(v.x, v.y);
                d[2*q]  = mn - mx[2*q];
            }
            {
                float mn = fminf(v.z, v.w);
                mx[2*q+1] = fmaxf(v.z, v.w);
                d[2*q+1]  = mn - mx[2*q+1];
            }
        }
    }

    float* __restrict__ o = &so[tid * 19];

    // ---- Phase 3: R0's proven scalar tree-PAIR loop (VGPR ~24 natural).
    #pragma unroll
    for (int tp = 0; tp < 9; ++tp) {
        const int t0 = 2 * tp, t1 = 2 * tp + 1;
        const float* wr0 = w + t0 * 19;
        const float* wr1 = w + t1 * 19;

        float y0[10], y1[10];
        #pragma unroll
        for (int k = 0; k < 10; ++k) {
            y0[k] = fmaf(wr0[k], d[k], mx[k]);
            y1[k] = fmaf(wr1[k], d[k], mx[k]);
        }

        float z0[5], z1[5];
        #pragma unroll
        for (int k = 0; k < 5; ++k) {
            z0[k] = mixf(y0[2*k], y0[2*k+1], wr0[10 + k]);
            z1[k] = mixf(y1[2*k], y1[2*k+1], wr1[10 + k]);
        }

        float u00 = mixf(z0[0], z0[1], wr0[15]);
        float u01 = mixf(z0[2], z0[3], wr0[16]);
        float u10 = mixf(z1[0], z1[1], wr1[15]);
        float u11 = mixf(z1[2], z1[3], wr1[16]);

        float v0 = mixf(u00, u01, wr0[17]);
        float v1 = mixf(u10, u11, wr1[17]);

        float r0 = mixf(v0, z0[4], wr0[18]);
        float r1 = mixf(v1, z1[4], wr1[18]);

        o[t0] = clampf(r0);
        o[t1] = clampf(r1);
    }

    // tree 18 (last, unpaired)
    {
        const float* wr = w + 18 * 19;
        float y[10];
        #pragma unroll
        for (int k = 0; k < 10; ++k)
            y[k] = fmaf(wr[k], d[k], mx[k]);
        float z[5];
        #pragma unroll
        for (int k = 0; k < 5; ++k)
            z[k] = mixf(y[2*k], y[2*k+1], wr[10 + k]);
        float u0 = mixf(z[0], z[1], wr[15]);
        float u1 = mixf(z[2], z[3], wr[16]);
        float v0 = mixf(u0, u1, wr[17]);
        float r  = mixf(v0, z[4], wr[18]);
        o[18] = clampf(r);
    }

    __syncthreads();

    // ---- Phase 4: cooperative coalesced copy-out: 1216 float4, nt stores.
    const int nDw    = B * 19;          // 1.9e7 fits int32
    const int baseDw = S0 * 19;         // divisible by 4
    const v4f* ls = reinterpret_cast<const v4f*>(so);

    #pragma unroll
    for (int i = tid; i < (BLK * 19) / 4; i += BLK) {
        int g = baseDw + i * 4;
        if (g + 3 < nDw) {
            __builtin_nontemporal_store(ls[i], reinterpret_cast<v4f*>(out + g));
        } else if (g < nDw) {
            v4f v4 = ls[i];
            out[g] = v4.x;
            if (g + 1 < nDw) out[g + 1] = v4.y;
            if (g + 2 < nDw) out[g + 2] = v4.z;
        }
    }
}

extern "C" void kernel_launch(void* const* d_in, const int* in_sizes, int n_in,
                              void* d_out, int out_size, void* d_ws, size_t ws_size,
                              hipStream_t stream) {
    // setup_inputs order: p1 (B,) int, p2 (B,) int, c20 (B,20) f32, w_raw (19,19) f32
    const float* c20   = (const float*)d_in[2];
    const float* w_raw = (const float*)d_in[3];
    float* out = (float*)d_out;
    float* w   = (float*)d_ws;   // 361 floats of scratch

    int B = in_sizes[0];

    sigmoid_w_kernel<<<1, 384, 0, stream>>>(w_raw, w);

    int grid = (B + BLK - 1) / BLK;
    tree_forward_kernel<<<grid, BLK, 0, stream>>>(c20, w, out, B);
}